// Round 9
// baseline (315.813 us; speedup 1.0000x reference)
//
#include <hip/hip_runtime.h>
#include <math.h>

#define N_NODES 50000
#define N_EDGES 800000
#define EP (N_EDGES + N_NODES)   // 850000 edges incl. self loops
#define NEG 0.2f
#define SCAN_BLOCKS 49           // ceil(50000/1024)
#define HB N_NODES               // nodes per head slice

typedef __attribute__((ext_vector_type(8))) short bf16x8;
typedef __attribute__((ext_vector_type(4))) float f32x4;
typedef __attribute__((ext_vector_type(2))) float f32x2;

// bf16 round-to-nearest-even from fp32
static __device__ __forceinline__ unsigned short bf16_rn(float f) {
    union { float f; unsigned int u; } v; v.f = f;
    unsigned int u = v.u;
    unsigned int r = (u + 0x7FFFu + ((u >> 16) & 1u)) >> 16;
    return (unsigned short)r;
}
// unpack 2 bf16 (packed in a dword) -> f32x2 {low, high}
static __device__ __forceinline__ f32x2 bf2_unpack(unsigned int u) {
    union { unsigned int i; float f; } a, b;
    a.i = u << 16; b.i = u & 0xFFFF0000u;
    return (f32x2){a.f, b.f};
}
static __device__ __forceinline__ float leaky_exp(float e) {
    e = (e > 0.f) ? e : NEG * e;
    return __expf(e);
}

// ---------------- CSR build ----------------

__global__ void k_hist(const int* __restrict__ ei, int* __restrict__ counts) {
    int e = blockIdx.x * 256 + threadIdx.x;
    if (e >= EP) return;
    int d = (e < N_EDGES) ? ei[N_EDGES + e] : (e - N_EDGES);
    atomicAdd(&counts[d], 1);
}

__global__ void k_scan_block(const int* __restrict__ counts, int* __restrict__ excl,
                             int* __restrict__ bsums) {
    __shared__ int wsum[4];
    int b = blockIdx.x, t = threadIdx.x;
    int lane = t & 63, w = t >> 6;
    int i0 = b * 1024 + t * 4;
    int v0 = (i0 + 0 < N_NODES) ? counts[i0 + 0] : 0;
    int v1 = (i0 + 1 < N_NODES) ? counts[i0 + 1] : 0;
    int v2 = (i0 + 2 < N_NODES) ? counts[i0 + 2] : 0;
    int v3 = (i0 + 3 < N_NODES) ? counts[i0 + 3] : 0;
    int s = v0 + v1 + v2 + v3;
    int incl = s;
    #pragma unroll
    for (int d = 1; d < 64; d <<= 1) {
        int u = __shfl_up(incl, d);
        if (lane >= d) incl += u;
    }
    if (lane == 63) wsum[w] = incl;
    __syncthreads();
    if (t == 0) {
        int run = 0;
        #pragma unroll
        for (int i = 0; i < 4; ++i) { int x = wsum[i]; wsum[i] = run; run += x; }
        bsums[b] = run;   // block total
    }
    __syncthreads();
    int base = wsum[w] + incl - s;   // exclusive prefix of this thread's chunk
    if (i0 + 0 < N_NODES) excl[i0 + 0] = base;
    if (i0 + 1 < N_NODES) excl[i0 + 1] = base + v0;
    if (i0 + 2 < N_NODES) excl[i0 + 2] = base + v0 + v1;
    if (i0 + 3 < N_NODES) excl[i0 + 3] = base + v0 + v1 + v2;
}

// scan_mid folded in: every block wave-scans the 49 block sums itself
__global__ void k_scan_add(int* __restrict__ row_ptr, const int* __restrict__ bsums) {
    __shared__ int soff;
    int b = blockIdx.x, t = threadIdx.x;
    if (t < 64) {
        int v = (t < SCAN_BLOCKS) ? bsums[t] : 0;
        int incl = v;
        #pragma unroll
        for (int d = 1; d < 64; d <<= 1) {
            int u = __shfl_up(incl, d);
            if (t >= d) incl += u;
        }
        if (t == b) soff = incl - v;   // exclusive prefix at block b
    }
    __syncthreads();
    int off = soff;
    int i0 = b * 1024 + t * 4;
    #pragma unroll
    for (int j = 0; j < 4; ++j)
        if (i0 + j < N_NODES) row_ptr[i0 + j] += off;
    if (b == 0 && t == 0) row_ptr[N_NODES] = EP;
}

// scatter + fused per-edge attention-p computation (all 8 heads at once).
// Runs AFTER k_gemm1m (needs node-major as1n/ad1n). Writes colb[pos]=s and
// pst[pos][0..7] = exp(leakyrelu(as1n[s][h] + ad1n[d][h])) (node-major, one
// 32B line-write per edge; the head-major transpose happens in k_pT).
__global__ void k_scatter(const int* __restrict__ ei, const int* __restrict__ row_ptr,
                          int* __restrict__ fill, int* __restrict__ colb,
                          const float* __restrict__ as1n, const float* __restrict__ ad1n,
                          float* __restrict__ pst) {
    int e = blockIdx.x * 256 + threadIdx.x;
    if (e >= EP) return;
    int s, d;
    if (e < N_EDGES) { s = ei[e]; d = ei[N_EDGES + e]; }
    else             { s = e - N_EDGES; d = s; }
    int pos = row_ptr[d] + atomicAdd(&fill[d], 1);
    colb[pos] = s;
    const float4* a4 = (const float4*)as1n;
    const float4* d4 = (const float4*)ad1n;
    float4 sa0 = a4[s * 2], sa1 = a4[s * 2 + 1];
    float4 da0 = d4[d * 2], da1 = d4[d * 2 + 1];
    float4 q0, q1;
    q0.x = leaky_exp(sa0.x + da0.x);
    q0.y = leaky_exp(sa0.y + da0.y);
    q0.z = leaky_exp(sa0.z + da0.z);
    q0.w = leaky_exp(sa0.w + da0.w);
    q1.x = leaky_exp(sa1.x + da1.x);
    q1.y = leaky_exp(sa1.y + da1.y);
    q1.z = leaky_exp(sa1.z + da1.z);
    q1.w = leaky_exp(sa1.w + da1.w);
    float4* pp = (float4*)(pst + (size_t)pos * 8);
    pp[0] = q0;
    pp[1] = q1;
}

// transpose pst[edge][8] -> pstT[8][EP]: both sides fully coalesced. Head-major
// p-streams make k_aggh's p-read a sequential 3.4MB stream per head instead of
// a strided walk over the whole 27.2MB (round-5's L2-capacity blowout).
__global__ void k_pT(const float* __restrict__ pst, float* __restrict__ pstT) {
    int e = blockIdx.x * 256 + threadIdx.x;
    if (e >= EP) return;
    const float4* p4 = (const float4*)(pst + (size_t)e * 8);
    float4 a = p4[0], b = p4[1];
    pstT[0 * EP + e] = a.x;
    pstT[1 * EP + e] = a.y;
    pstT[2 * EP + e] = a.z;
    pstT[3 * EP + e] = a.w;
    pstT[4 * EP + e] = b.x;
    pstT[5 * EP + e] = b.y;
    pstT[6 * EP + e] = b.z;
    pstT[7 * EP + e] = b.w;
}

// ---------------- W1 -> MFMA B-fragment order (pi-permuted), bf16 ----------------
__global__ void k_cvtWfrag(const float* __restrict__ W1, bf16x8* __restrict__ Wfrag) {
    int ft = blockIdx.x * 256 + threadIdx.x;   // 8192 frag-lanes
    int c = ft >> 10, rem = ft & 1023;
    int nt = rem >> 6, l = rem & 63;
    int n = (l & 15) * 16 + nt;
    int k0 = c * 32 + (l >> 4) * 8;
    bf16x8 f;
    #pragma unroll
    for (int j = 0; j < 8; ++j)
        f[j] = (short)bf16_rn(W1[(k0 + j) * 256 + n]);
    Wfrag[ft] = f;
}

// ---------------- Layer 1 GEMM via bf16 MFMA + fused attention logits ----------------
// Output layout: head-major slices xph[h][node][32ch] bf16 (per-head 3.2MB working
// set fits one XCD's 4MB L2). as1/ad1 stored node-major: as1n[node][8] (32B - one
// line-request serves all 8 heads in the fused k_scatter).
#define GM_GRID 782   // ceil(50000/64)
__global__ __launch_bounds__(256) void
k_gemm1m(const float* __restrict__ x, const bf16x8* __restrict__ Wfrag,
         unsigned short* __restrict__ xph,
         const float* __restrict__ asrc, const float* __restrict__ adst,
         float* __restrict__ as1n, float* __restrict__ ad1n) {
    __shared__ bf16x8 lds[1024];   // one chunk of B frags: 16 KB
    int t = threadIdx.x, l = t & 63, w = t >> 6;
    int rowbase = blockIdx.x * 64 + w * 16;
    int m = l & 15, kg = l >> 4;

    f32x4 acc[16];
    #pragma unroll
    for (int nt = 0; nt < 16; ++nt)
        acc[nt] = (f32x4){0.f, 0.f, 0.f, 0.f};

    int r0 = rowbase + m;
    if (r0 > N_NODES - 1) r0 = N_NODES - 1;   // clamp (results unused)
    const float4* x4 = (const float4*)x;

    for (int c = 0; c < 8; ++c) {
        __syncthreads();   // previous chunk's B reads done before overwrite
        const bf16x8* src = Wfrag + c * 1024;
        #pragma unroll
        for (int q = 0; q < 4; ++q)
            lds[q * 256 + t] = src[q * 256 + t];
        __syncthreads();

        int kb = (c * 32 + kg * 8) >> 2;       // float4 col index
        float4 xa0 = x4[r0 * 64 + kb], xb0 = x4[r0 * 64 + kb + 1];
        bf16x8 aF0;
        aF0[0] = (short)bf16_rn(xa0.x); aF0[1] = (short)bf16_rn(xa0.y);
        aF0[2] = (short)bf16_rn(xa0.z); aF0[3] = (short)bf16_rn(xa0.w);
        aF0[4] = (short)bf16_rn(xb0.x); aF0[5] = (short)bf16_rn(xb0.y);
        aF0[6] = (short)bf16_rn(xb0.z); aF0[7] = (short)bf16_rn(xb0.w);

        #pragma unroll
        for (int nt = 0; nt < 16; ++nt) {
            bf16x8 bF = lds[nt * 64 + l];
            acc[nt] = __builtin_amdgcn_mfma_f32_16x16x32_bf16(aF0, bF, acc[nt], 0, 0, 0);
        }
    }

    // epilogue: lane holds channels cbase*16 + nt (nt=0..15) of rows rq*4+reg
    int cbase = l & 15, rq = l >> 4;
    int head = cbase >> 1, hhalf = cbase & 1;   // 16-ch half within head
    float asV[16], adV[16];
    #pragma unroll
    for (int q = 0; q < 4; ++q) {
        float4 sa = ((const float4*)asrc)[cbase * 4 + q];
        float4 da = ((const float4*)adst)[cbase * 4 + q];
        asV[q * 4 + 0] = sa.x; asV[q * 4 + 1] = sa.y; asV[q * 4 + 2] = sa.z; asV[q * 4 + 3] = sa.w;
        adV[q * 4 + 0] = da.x; adV[q * 4 + 1] = da.y; adV[q * 4 + 2] = da.z; adV[q * 4 + 3] = da.w;
    }
    #pragma unroll
    for (int reg = 0; reg < 4; ++reg) {
        int gr = rowbase + rq * 4 + reg;
        unsigned int ob[8];
        float ps = 0.f, pd = 0.f;
        #pragma unroll
        for (int q = 0; q < 8; ++q) {
            float v0 = acc[2 * q][reg], v1 = acc[2 * q + 1][reg];
            ob[q] = (unsigned int)bf16_rn(v0) | ((unsigned int)bf16_rn(v1) << 16);
            ps = fmaf(v0, asV[2 * q], ps);     ps = fmaf(v1, asV[2 * q + 1], ps);
            pd = fmaf(v0, adV[2 * q], pd);     pd = fmaf(v1, adV[2 * q + 1], pd);
        }
        ps += __shfl_xor(ps, 1);
        pd += __shfl_xor(pd, 1);
        if (gr < N_NODES) {
            // head-major slice write: [head][node][32ch], this lane's 16-ch half
            uint4* dst = (uint4*)(xph + (head * HB + gr) * 32 + hhalf * 16);
            dst[0] = make_uint4(ob[0], ob[1], ob[2], ob[3]);
            dst[1] = make_uint4(ob[4], ob[5], ob[6], ob[7]);
            if (hhalf == 0) {
                as1n[gr * 8 + head] = ps;   // node-major for fused k_scatter
                ad1n[gr * 8 + head] = pd;
            }
        }
    }
}

// ---------------- head-sliced layer-1 softmax-aggregate + ReLU + proj2 partial ----
// head = blockIdx.x & 7 (XCD-pinned: per-head 3.2MB xph slice is L2-resident).
// Lane = (node, ch-sub): 64 lanes = 16 nodes x 4 subs. Round-8 structure:
// NO shuffles in the inner loop - each lane loads the quad-uniform (s,p)
// streams directly (colb[j+e2] / pstT[h][j+e2] identical across the quad, so
// the TA broadcasts them). Per 8-edge batch: 8 colb + 8 pT independent loads
// issued up front (deep MLP, clamped addresses), then 8 exec-guarded 16B row
// gathers. den needs no reduction (every lane sees every p). Regular cached
// loads (round-7's NT loads de-allocated reused stream lines: 85us regression).
#define AGH_GRID (782 * 8)   // 782 blocks/head (64 nodes each) x 8 heads
__global__ __launch_bounds__(256) void
k_aggh(const uint4* __restrict__ xph4, const float* __restrict__ pstT,
       const int* __restrict__ row_ptr, const int* __restrict__ colb,
       const float* __restrict__ b1, const float* __restrict__ W2,
       float2* __restrict__ hpartT) {
    int t = threadIdx.x, l = t & 63, w = t >> 6;
    int bid = blockIdx.x;
    int h = bid & 7;                    // XCD-pinned head
    int g = bid >> 3;                   // node-group 0..781
    int node = g * 64 + w * 16 + (l >> 2);
    int sub = l & 3;                    // channels h*32 + sub*8 .. +7
    bool alive = node < N_NODES;
    int nc = alive ? node : (N_NODES - 1);
    int start = row_ptr[nc], end = row_ptr[nc + 1];
    if (!alive) end = start;
    const uint4* xb = xph4 + (size_t)h * (HB * 4);
    const float* pT = pstT + (size_t)h * EP;

    f32x2 a0 = {0.f, 0.f}, a1 = {0.f, 0.f}, a2 = {0.f, 0.f}, a3 = {0.f, 0.f};
    float den = 0.f;

    for (int j = start; j < end; j += 8) {
        int sA[8]; float pA[8];
        // phase 1: 16 independent cached loads (quad-uniform addresses)
        #pragma unroll
        for (int e2 = 0; e2 < 8; ++e2) {
            int jj = j + e2;
            int jc = (jj < end) ? jj : start;     // clamp: loads stay valid
            sA[e2] = colb[jc];
            float pv = pT[jc];
            pA[e2] = (jj < end) ? pv : 0.f;       // tail contributes nothing
        }
        // phase 2: accumulate den (each lane sees every p - no reduction later)
        den += ((pA[0] + pA[1]) + (pA[2] + pA[3]))
             + ((pA[4] + pA[5]) + (pA[6] + pA[7]));
        // phase 3: guarded row gathers + FMAs
        #pragma unroll
        for (int e2 = 0; e2 < 8; ++e2) {
            if (j + e2 < end) {          // quad-uniform guard
                uint4 r = xb[(size_t)sA[e2] * 4 + sub];
                f32x2 q = {pA[e2], pA[e2]};
                a0 += q * bf2_unpack(r.x);
                a1 += q * bf2_unpack(r.y);
                a2 += q * bf2_unpack(r.z);
                a3 += q * bf2_unpack(r.w);
            }
        }
    }

    // epilogue: softmax-normalize, +bias, ReLU, proj2 partial for this head
    float inv = 1.f / den;               // den>0 (self-loop guaranteed)
    const float4* b4 = (const float4*)b1;
    float4 ba = b4[h * 8 + sub * 2 + 0];
    float4 bb = b4[h * 8 + sub * 2 + 1];
    float o0 = fmaxf(fmaf(a0[0], inv, ba.x), 0.f);
    float o1 = fmaxf(fmaf(a0[1], inv, ba.y), 0.f);
    float o2 = fmaxf(fmaf(a1[0], inv, ba.z), 0.f);
    float o3 = fmaxf(fmaf(a1[1], inv, ba.w), 0.f);
    float o4 = fmaxf(fmaf(a2[0], inv, bb.x), 0.f);
    float o5 = fmaxf(fmaf(a2[1], inv, bb.y), 0.f);
    float o6 = fmaxf(fmaf(a3[0], inv, bb.z), 0.f);
    float o7 = fmaxf(fmaf(a3[1], inv, bb.w), 0.f);
    // W2 row-major (256,2): rows rb = h*32 + sub*8 .. +7; float4 = 2 rows
    const float4* W4 = (const float4*)W2;
    float4 wA = W4[h * 16 + sub * 4 + 0];
    float4 wB = W4[h * 16 + sub * 4 + 1];
    float4 wC = W4[h * 16 + sub * 4 + 2];
    float4 wD = W4[h * 16 + sub * 4 + 3];
    float d0 = o0 * wA.x + o1 * wA.z + o2 * wB.x + o3 * wB.z
             + o4 * wC.x + o5 * wC.z + o6 * wD.x + o7 * wD.z;
    float d1 = o0 * wA.y + o1 * wA.w + o2 * wB.y + o3 * wB.w
             + o4 * wC.y + o5 * wC.w + o6 * wD.y + o7 * wD.w;
    // reduce across the node's 4 subs (lanes 4n..4n+3)
    d0 += __shfl_xor(d0, 1);  d0 += __shfl_xor(d0, 2);
    d1 += __shfl_xor(d1, 1);  d1 += __shfl_xor(d1, 2);
    if (sub == 0 && alive)
        hpartT[(size_t)h * N_NODES + node] = (float2){d0, d1};   // coalesced per wave
}

// ---------------- sum head partials -> packed layer-2 record ----------------
// pk[n] = {xp2.x, xp2.y, as2, ad2}: one 16B gather per edge in k_agg2.
// hpartT is head-major [8][N]; each plane read coalesced.
__global__ void k_post(const float2* __restrict__ hpartT, const float* __restrict__ as2w,
                       const float* __restrict__ ad2w, float4* __restrict__ pk) {
    int n = blockIdx.x * 256 + threadIdx.x;
    if (n >= N_NODES) return;
    float d0 = 0.f, d1 = 0.f;
    #pragma unroll
    for (int h = 0; h < 8; ++h) {
        float2 v = hpartT[(size_t)h * N_NODES + n];
        d0 += v.x;
        d1 += v.y;
    }
    float4 r;
    r.x = d0;
    r.y = d1;
    r.z = d0 * as2w[0] + d1 * as2w[1];   // as2
    r.w = d0 * ad2w[0] + d1 * ad2w[1];   // ad2
    pk[n] = r;
}

// ---------------- fused segment-softmax + aggregate, layer 2 (2 channels) ----------------
__global__ void k_agg2(const float4* __restrict__ pk, const int* __restrict__ row_ptr,
                       const int* __restrict__ colb, const float* __restrict__ b2,
                       float* __restrict__ out) {
    int t = threadIdx.x;
    int g = t >> 4, lane = t & 15;
    int n = blockIdx.x * 16 + g;
    int start = row_ptr[n], end = row_ptr[n + 1];
    float adn = pk[n].w;
    float a0 = 0.f, a1 = 0.f, den = 0.f;
    for (int j = start + lane; j < end; j += 16) {
        int s = colb[j];
        float4 r = pk[s];
        float e = r.z + adn;
        e = (e > 0.f) ? e : NEG * e;
        float p = __expf(e);
        den += p;
        a0 = fmaf(p, r.x, a0);
        a1 = fmaf(p, r.y, a1);
    }
    #pragma unroll
    for (int m = 1; m < 16; m <<= 1) {
        a0 += __shfl_xor(a0, m);
        a1 += __shfl_xor(a1, m);
        den += __shfl_xor(den, m);
    }
    if (lane == 0) {
        out[2 * n] = a0 / den + b2[0];
        out[2 * n + 1] = a1 / den + b2[1];
    }
}

extern "C" void kernel_launch(void* const* d_in, const int* in_sizes, int n_in,
                              void* d_out, int out_size, void* d_ws, size_t ws_size,
                              hipStream_t stream) {
    const float* x     = (const float*)d_in[0];
    const int*   ei    = (const int*)d_in[1];
    const float* W1    = (const float*)d_in[2];
    const float* asrc1 = (const float*)d_in[3];
    const float* adst1 = (const float*)d_in[4];
    const float* b1    = (const float*)d_in[5];
    const float* W2    = (const float*)d_in[6];
    const float* asrc2 = (const float*)d_in[7];
    const float* adst2 = (const float*)d_in[8];
    const float* b2    = (const float*)d_in[9];
    float* out = (float*)d_out;

    char* ws = (char*)d_ws;
    unsigned short* xph = (unsigned short*)(ws + 0);  // 25,600,000 B (bf16, head-major)
    bf16x8* Wfrag  = (bf16x8*)(ws + 25600000);      //    131,072 B (B frags)
    float2* hpartT = (float2*)(ws + 25800000);      //  3,200,000 B (head-major proj2 partials)
    float* pst     = (float*)(ws + 29000000);       // 27,200,000 B (per-edge p, node-major)
    float* pstT    = (float*)(ws + 56200000);       // 27,200,000 B (per-edge p, head-major)
    float* as1n    = (float*)(ws + 102400000);      //  1,600,000 B ([50000][8])
    float* ad1n    = (float*)(ws + 104000000);      //  1,600,000 B ([50000][8])
    float4* pk     = (float4*)(ws + 105600000);     //    800,000 B (packed layer-2 records)
    int*   counts  = (int*)  (ws + 106400000);      //    200,000 B
    int*   fill    = (int*)  (ws + 106600000);      //    200,000 B (contig w/ counts)
    int*   row_ptr = (int*)  (ws + 106800000);      //    200,064 B
    int*   colb    = (int*)  (ws + 107000064);      //  3,400,000 B
    int*   bsums   = (int*)  (ws + 110400064);      //        256 B

    hipMemsetAsync(counts, 0, 400000, stream);      // counts + fill

    int egrid = (EP + 255) / 256;
    k_hist      <<<egrid,       256, 0, stream>>>(ei, counts);
    k_scan_block<<<SCAN_BLOCKS, 256, 0, stream>>>(counts, row_ptr, bsums);
    k_scan_add  <<<SCAN_BLOCKS, 256, 0, stream>>>(row_ptr, bsums);

    k_cvtWfrag  <<<32,     256, 0, stream>>>(W1, Wfrag);
    k_gemm1m   <<<GM_GRID, 256, 0, stream>>>(x, Wfrag, xph, asrc1, adst1, as1n, ad1n);
    // scatter AFTER gemm: fuses per-edge p computation for all 8 heads
    k_scatter   <<<egrid,   256, 0, stream>>>(ei, row_ptr, fill, colb, as1n, ad1n, pst);
    k_pT        <<<egrid,   256, 0, stream>>>(pst, pstT);
    k_aggh     <<<AGH_GRID, 256, 0, stream>>>((const uint4*)xph, pstT, row_ptr, colb,
                                              b1, W2, hpartT);
    k_post     <<<196,     256, 0, stream>>>(hpartT, asrc2, adst2, pk);
    k_agg2     <<<3125,    256, 0, stream>>>(pk, row_ptr, colb, b2, out);
}

// Round 10
// 302.985 us; speedup vs baseline: 1.0423x; 1.0423x over previous
//
#include <hip/hip_runtime.h>
#include <math.h>

#define N_NODES 50000
#define N_EDGES 800000
#define EP (N_EDGES + N_NODES)   // 850000 edges incl. self loops
#define NEG 0.2f
#define SCAN_BLOCKS 49           // ceil(50000/1024)
#define HB N_NODES               // nodes per head slice

typedef __attribute__((ext_vector_type(8))) short bf16x8;
typedef __attribute__((ext_vector_type(4))) float f32x4;
typedef __attribute__((ext_vector_type(2))) float f32x2;

// bf16 round-to-nearest-even from fp32
static __device__ __forceinline__ unsigned short bf16_rn(float f) {
    union { float f; unsigned int u; } v; v.f = f;
    unsigned int u = v.u;
    unsigned int r = (u + 0x7FFFu + ((u >> 16) & 1u)) >> 16;
    return (unsigned short)r;
}
// unpack 2 bf16 (packed in a dword) -> f32x2 {low, high}
static __device__ __forceinline__ f32x2 bf2_unpack(unsigned int u) {
    union { unsigned int i; float f; } a, b;
    a.i = u << 16; b.i = u & 0xFFFF0000u;
    return (f32x2){a.f, b.f};
}
static __device__ __forceinline__ float leaky_exp(float e) {
    e = (e > 0.f) ? e : NEG * e;
    return __expf(e);
}

// ---------------- CSR build ----------------

__global__ void k_hist(const int* __restrict__ ei, int* __restrict__ counts) {
    int e = blockIdx.x * 256 + threadIdx.x;
    if (e >= EP) return;
    int d = (e < N_EDGES) ? ei[N_EDGES + e] : (e - N_EDGES);
    atomicAdd(&counts[d], 1);
}

__global__ void k_scan_block(const int* __restrict__ counts, int* __restrict__ excl,
                             int* __restrict__ bsums) {
    __shared__ int wsum[4];
    int b = blockIdx.x, t = threadIdx.x;
    int lane = t & 63, w = t >> 6;
    int i0 = b * 1024 + t * 4;
    int v0 = (i0 + 0 < N_NODES) ? counts[i0 + 0] : 0;
    int v1 = (i0 + 1 < N_NODES) ? counts[i0 + 1] : 0;
    int v2 = (i0 + 2 < N_NODES) ? counts[i0 + 2] : 0;
    int v3 = (i0 + 3 < N_NODES) ? counts[i0 + 3] : 0;
    int s = v0 + v1 + v2 + v3;
    int incl = s;
    #pragma unroll
    for (int d = 1; d < 64; d <<= 1) {
        int u = __shfl_up(incl, d);
        if (lane >= d) incl += u;
    }
    if (lane == 63) wsum[w] = incl;
    __syncthreads();
    if (t == 0) {
        int run = 0;
        #pragma unroll
        for (int i = 0; i < 4; ++i) { int x = wsum[i]; wsum[i] = run; run += x; }
        bsums[b] = run;   // block total
    }
    __syncthreads();
    int base = wsum[w] + incl - s;   // exclusive prefix of this thread's chunk
    if (i0 + 0 < N_NODES) excl[i0 + 0] = base;
    if (i0 + 1 < N_NODES) excl[i0 + 1] = base + v0;
    if (i0 + 2 < N_NODES) excl[i0 + 2] = base + v0 + v1;
    if (i0 + 3 < N_NODES) excl[i0 + 3] = base + v0 + v1 + v2;
}

// scan_mid folded in: every block wave-scans the 49 block sums itself
__global__ void k_scan_add(int* __restrict__ row_ptr, const int* __restrict__ bsums) {
    __shared__ int soff;
    int b = blockIdx.x, t = threadIdx.x;
    if (t < 64) {
        int v = (t < SCAN_BLOCKS) ? bsums[t] : 0;
        int incl = v;
        #pragma unroll
        for (int d = 1; d < 64; d <<= 1) {
            int u = __shfl_up(incl, d);
            if (t >= d) incl += u;
        }
        if (t == b) soff = incl - v;   // exclusive prefix at block b
    }
    __syncthreads();
    int off = soff;
    int i0 = b * 1024 + t * 4;
    #pragma unroll
    for (int j = 0; j < 4; ++j)
        if (i0 + j < N_NODES) row_ptr[i0 + j] += off;
    if (b == 0 && t == 0) row_ptr[N_NODES] = EP;
}

// scatter + fused per-edge attention-p computation (all 8 heads at once).
// Runs AFTER k_gemm1m (needs node-major as1n/ad1n). Writes colb[pos]=s and
// pst[pos][0..7] = exp(leakyrelu(as1n[s][h] + ad1n[d][h])) (node-major, one
// 32B line-write per edge; the head-major transpose happens in k_pT).
__global__ void k_scatter(const int* __restrict__ ei, const int* __restrict__ row_ptr,
                          int* __restrict__ fill, int* __restrict__ colb,
                          const float* __restrict__ as1n, const float* __restrict__ ad1n,
                          float* __restrict__ pst) {
    int e = blockIdx.x * 256 + threadIdx.x;
    if (e >= EP) return;
    int s, d;
    if (e < N_EDGES) { s = ei[e]; d = ei[N_EDGES + e]; }
    else             { s = e - N_EDGES; d = s; }
    int pos = row_ptr[d] + atomicAdd(&fill[d], 1);
    colb[pos] = s;
    const float4* a4 = (const float4*)as1n;
    const float4* d4 = (const float4*)ad1n;
    float4 sa0 = a4[s * 2], sa1 = a4[s * 2 + 1];
    float4 da0 = d4[d * 2], da1 = d4[d * 2 + 1];
    float4 q0, q1;
    q0.x = leaky_exp(sa0.x + da0.x);
    q0.y = leaky_exp(sa0.y + da0.y);
    q0.z = leaky_exp(sa0.z + da0.z);
    q0.w = leaky_exp(sa0.w + da0.w);
    q1.x = leaky_exp(sa1.x + da1.x);
    q1.y = leaky_exp(sa1.y + da1.y);
    q1.z = leaky_exp(sa1.z + da1.z);
    q1.w = leaky_exp(sa1.w + da1.w);
    float4* pp = (float4*)(pst + (size_t)pos * 8);
    pp[0] = q0;
    pp[1] = q1;
}

// transpose pst[edge][8] -> pstT[8][EP]: both sides fully coalesced. Head-major
// p-streams make k_aggh's p-read a sequential 3.4MB stream per head instead of
// a strided walk over the whole 27.2MB (round-5's L2-capacity blowout).
__global__ void k_pT(const float* __restrict__ pst, float* __restrict__ pstT) {
    int e = blockIdx.x * 256 + threadIdx.x;
    if (e >= EP) return;
    const float4* p4 = (const float4*)(pst + (size_t)e * 8);
    float4 a = p4[0], b = p4[1];
    pstT[0 * EP + e] = a.x;
    pstT[1 * EP + e] = a.y;
    pstT[2 * EP + e] = a.z;
    pstT[3 * EP + e] = a.w;
    pstT[4 * EP + e] = b.x;
    pstT[5 * EP + e] = b.y;
    pstT[6 * EP + e] = b.z;
    pstT[7 * EP + e] = b.w;
}

// ---------------- W1 -> MFMA B-fragment order (pi-permuted), bf16 ----------------
__global__ void k_cvtWfrag(const float* __restrict__ W1, bf16x8* __restrict__ Wfrag) {
    int ft = blockIdx.x * 256 + threadIdx.x;   // 8192 frag-lanes
    int c = ft >> 10, rem = ft & 1023;
    int nt = rem >> 6, l = rem & 63;
    int n = (l & 15) * 16 + nt;
    int k0 = c * 32 + (l >> 4) * 8;
    bf16x8 f;
    #pragma unroll
    for (int j = 0; j < 8; ++j)
        f[j] = (short)bf16_rn(W1[(k0 + j) * 256 + n]);
    Wfrag[ft] = f;
}

// ---------------- Layer 1 GEMM via bf16 MFMA + fused attention logits ----------------
// Output layout: head-major slices xph[h][node][32ch] bf16 (per-head 3.2MB working
// set fits one XCD's 4MB L2). as1/ad1 stored node-major: as1n[node][8] (32B - one
// line-request serves all 8 heads in the fused k_scatter).
#define GM_GRID 782   // ceil(50000/64)
__global__ __launch_bounds__(256) void
k_gemm1m(const float* __restrict__ x, const bf16x8* __restrict__ Wfrag,
         unsigned short* __restrict__ xph,
         const float* __restrict__ asrc, const float* __restrict__ adst,
         float* __restrict__ as1n, float* __restrict__ ad1n) {
    __shared__ bf16x8 lds[1024];   // one chunk of B frags: 16 KB
    int t = threadIdx.x, l = t & 63, w = t >> 6;
    int rowbase = blockIdx.x * 64 + w * 16;
    int m = l & 15, kg = l >> 4;

    f32x4 acc[16];
    #pragma unroll
    for (int nt = 0; nt < 16; ++nt)
        acc[nt] = (f32x4){0.f, 0.f, 0.f, 0.f};

    int r0 = rowbase + m;
    if (r0 > N_NODES - 1) r0 = N_NODES - 1;   // clamp (results unused)
    const float4* x4 = (const float4*)x;

    for (int c = 0; c < 8; ++c) {
        __syncthreads();   // previous chunk's B reads done before overwrite
        const bf16x8* src = Wfrag + c * 1024;
        #pragma unroll
        for (int q = 0; q < 4; ++q)
            lds[q * 256 + t] = src[q * 256 + t];
        __syncthreads();

        int kb = (c * 32 + kg * 8) >> 2;       // float4 col index
        float4 xa0 = x4[r0 * 64 + kb], xb0 = x4[r0 * 64 + kb + 1];
        bf16x8 aF0;
        aF0[0] = (short)bf16_rn(xa0.x); aF0[1] = (short)bf16_rn(xa0.y);
        aF0[2] = (short)bf16_rn(xa0.z); aF0[3] = (short)bf16_rn(xa0.w);
        aF0[4] = (short)bf16_rn(xb0.x); aF0[5] = (short)bf16_rn(xb0.y);
        aF0[6] = (short)bf16_rn(xb0.z); aF0[7] = (short)bf16_rn(xb0.w);

        #pragma unroll
        for (int nt = 0; nt < 16; ++nt) {
            bf16x8 bF = lds[nt * 64 + l];
            acc[nt] = __builtin_amdgcn_mfma_f32_16x16x32_bf16(aF0, bF, acc[nt], 0, 0, 0);
        }
    }

    // epilogue: lane holds channels cbase*16 + nt (nt=0..15) of rows rq*4+reg
    int cbase = l & 15, rq = l >> 4;
    int head = cbase >> 1, hhalf = cbase & 1;   // 16-ch half within head
    float asV[16], adV[16];
    #pragma unroll
    for (int q = 0; q < 4; ++q) {
        float4 sa = ((const float4*)asrc)[cbase * 4 + q];
        float4 da = ((const float4*)adst)[cbase * 4 + q];
        asV[q * 4 + 0] = sa.x; asV[q * 4 + 1] = sa.y; asV[q * 4 + 2] = sa.z; asV[q * 4 + 3] = sa.w;
        adV[q * 4 + 0] = da.x; adV[q * 4 + 1] = da.y; adV[q * 4 + 2] = da.z; adV[q * 4 + 3] = da.w;
    }
    #pragma unroll
    for (int reg = 0; reg < 4; ++reg) {
        int gr = rowbase + rq * 4 + reg;
        unsigned int ob[8];
        float ps = 0.f, pd = 0.f;
        #pragma unroll
        for (int q = 0; q < 8; ++q) {
            float v0 = acc[2 * q][reg], v1 = acc[2 * q + 1][reg];
            ob[q] = (unsigned int)bf16_rn(v0) | ((unsigned int)bf16_rn(v1) << 16);
            ps = fmaf(v0, asV[2 * q], ps);     ps = fmaf(v1, asV[2 * q + 1], ps);
            pd = fmaf(v0, adV[2 * q], pd);     pd = fmaf(v1, adV[2 * q + 1], pd);
        }
        ps += __shfl_xor(ps, 1);
        pd += __shfl_xor(pd, 1);
        if (gr < N_NODES) {
            // head-major slice write: [head][node][32ch], this lane's 16-ch half
            uint4* dst = (uint4*)(xph + (head * HB + gr) * 32 + hhalf * 16);
            dst[0] = make_uint4(ob[0], ob[1], ob[2], ob[3]);
            dst[1] = make_uint4(ob[4], ob[5], ob[6], ob[7]);
            if (hhalf == 0) {
                as1n[gr * 8 + head] = ps;   // node-major for fused k_scatter
                ad1n[gr * 8 + head] = pd;
            }
        }
    }
}

// ---------------- head-sliced layer-1 softmax-aggregate + ReLU + proj2 partial ----
// head = blockIdx.x & 7 (XCD-pinned: per-head 3.2MB xph slice is L2-resident).
// Lane = (node, ch-sub): 64 lanes = 16 nodes x 4 subs. Round-10 structure =
// round-9's no-shuffle quad-uniform stream loads + round-6's one-batch-ahead
// SOFTWARE PIPELINE: batch j+8's 16 stream loads are issued while batch j's
// gathers+FMAs execute, so the colb->gather dependency never sits on the
// critical path. Double-buffered in NAMED register sets (sA/pA vs sB/pB,
// manually 2x-unrolled loop) so all indexing is compile-time (no scratch).
#define AGH_GRID (782 * 8)   // 782 blocks/head (64 nodes each) x 8 heads
__global__ __launch_bounds__(256) void
k_aggh(const uint4* __restrict__ xph4, const float* __restrict__ pstT,
       const int* __restrict__ row_ptr, const int* __restrict__ colb,
       const float* __restrict__ b1, const float* __restrict__ W2,
       float2* __restrict__ hpartT) {
    int t = threadIdx.x, l = t & 63, w = t >> 6;
    int bid = blockIdx.x;
    int h = bid & 7;                    // XCD-pinned head
    int g = bid >> 3;                   // node-group 0..781
    int node = g * 64 + w * 16 + (l >> 2);
    int sub = l & 3;                    // channels h*32 + sub*8 .. +7
    bool alive = node < N_NODES;
    int nc = alive ? node : (N_NODES - 1);
    int start = row_ptr[nc], end = row_ptr[nc + 1];
    if (!alive) end = start;
    const uint4* xb = xph4 + (size_t)h * (HB * 4);
    const float* pT = pstT + (size_t)h * EP;

    f32x2 a0 = {0.f, 0.f}, a1 = {0.f, 0.f}, a2 = {0.f, 0.f}, a3 = {0.f, 0.f};
    float den = 0.f;

    int sA0, sA1, sA2, sA3, sA4, sA5, sA6, sA7;
    float pA0, pA1, pA2, pA3, pA4, pA5, pA6, pA7;
    int sB0, sB1, sB2, sB3, sB4, sB5, sB6, sB7;
    float pB0, pB1, pB2, pB3, pB4, pB5, pB6, pB7;

#define LOAD_BATCH(S0,S1,S2,S3,S4,S5,S6,S7, P0,P1,P2,P3,P4,P5,P6,P7, JB)      \
    {                                                                          \
        int jj, jc;                                                            \
        jj = (JB) + 0; jc = (jj < end) ? jj : start;                           \
        S0 = colb[jc]; P0 = (jj < end) ? pT[jc] : 0.f;                         \
        jj = (JB) + 1; jc = (jj < end) ? jj : start;                           \
        S1 = colb[jc]; P1 = (jj < end) ? pT[jc] : 0.f;                         \
        jj = (JB) + 2; jc = (jj < end) ? jj : start;                           \
        S2 = colb[jc]; P2 = (jj < end) ? pT[jc] : 0.f;                         \
        jj = (JB) + 3; jc = (jj < end) ? jj : start;                           \
        S3 = colb[jc]; P3 = (jj < end) ? pT[jc] : 0.f;                         \
        jj = (JB) + 4; jc = (jj < end) ? jj : start;                           \
        S4 = colb[jc]; P4 = (jj < end) ? pT[jc] : 0.f;                         \
        jj = (JB) + 5; jc = (jj < end) ? jj : start;                           \
        S5 = colb[jc]; P5 = (jj < end) ? pT[jc] : 0.f;                         \
        jj = (JB) + 6; jc = (jj < end) ? jj : start;                           \
        S6 = colb[jc]; P6 = (jj < end) ? pT[jc] : 0.f;                         \
        jj = (JB) + 7; jc = (jj < end) ? jj : start;                           \
        S7 = colb[jc]; P7 = (jj < end) ? pT[jc] : 0.f;                         \
    }

#define PROC_BATCH(S0,S1,S2,S3,S4,S5,S6,S7, P0,P1,P2,P3,P4,P5,P6,P7, JB)      \
    {                                                                          \
        den += ((P0 + P1) + (P2 + P3)) + ((P4 + P5) + (P6 + P7));              \
        if ((JB) + 0 < end) { uint4 r = xb[(size_t)S0 * 4 + sub];              \
            f32x2 q = {P0, P0};                                                \
            a0 += q * bf2_unpack(r.x); a1 += q * bf2_unpack(r.y);              \
            a2 += q * bf2_unpack(r.z); a3 += q * bf2_unpack(r.w); }            \
        if ((JB) + 1 < end) { uint4 r = xb[(size_t)S1 * 4 + sub];              \
            f32x2 q = {P1, P1};                                                \
            a0 += q * bf2_unpack(r.x); a1 += q * bf2_unpack(r.y);              \
            a2 += q * bf2_unpack(r.z); a3 += q * bf2_unpack(r.w); }            \
        if ((JB) + 2 < end) { uint4 r = xb[(size_t)S2 * 4 + sub];              \
            f32x2 q = {P2, P2};                                                \
            a0 += q * bf2_unpack(r.x); a1 += q * bf2_unpack(r.y);              \
            a2 += q * bf2_unpack(r.z); a3 += q * bf2_unpack(r.w); }            \
        if ((JB) + 3 < end) { uint4 r = xb[(size_t)S3 * 4 + sub];              \
            f32x2 q = {P3, P3};                                                \
            a0 += q * bf2_unpack(r.x); a1 += q * bf2_unpack(r.y);              \
            a2 += q * bf2_unpack(r.z); a3 += q * bf2_unpack(r.w); }            \
        if ((JB) + 4 < end) { uint4 r = xb[(size_t)S4 * 4 + sub];              \
            f32x2 q = {P4, P4};                                                \
            a0 += q * bf2_unpack(r.x); a1 += q * bf2_unpack(r.y);              \
            a2 += q * bf2_unpack(r.z); a3 += q * bf2_unpack(r.w); }            \
        if ((JB) + 5 < end) { uint4 r = xb[(size_t)S5 * 4 + sub];              \
            f32x2 q = {P5, P5};                                                \
            a0 += q * bf2_unpack(r.x); a1 += q * bf2_unpack(r.y);              \
            a2 += q * bf2_unpack(r.z); a3 += q * bf2_unpack(r.w); }            \
        if ((JB) + 6 < end) { uint4 r = xb[(size_t)S6 * 4 + sub];              \
            f32x2 q = {P6, P6};                                                \
            a0 += q * bf2_unpack(r.x); a1 += q * bf2_unpack(r.y);              \
            a2 += q * bf2_unpack(r.z); a3 += q * bf2_unpack(r.w); }            \
        if ((JB) + 7 < end) { uint4 r = xb[(size_t)S7 * 4 + sub];              \
            f32x2 q = {P7, P7};                                                \
            a0 += q * bf2_unpack(r.x); a1 += q * bf2_unpack(r.y);              \
            a2 += q * bf2_unpack(r.z); a3 += q * bf2_unpack(r.w); }            \
    }

    int j = start;
    if (j < end) {
        LOAD_BATCH(sA0,sA1,sA2,sA3,sA4,sA5,sA6,sA7,
                   pA0,pA1,pA2,pA3,pA4,pA5,pA6,pA7, j)
        for (;;) {
            int jn = j + 8;
            if (jn < end)
                LOAD_BATCH(sB0,sB1,sB2,sB3,sB4,sB5,sB6,sB7,
                           pB0,pB1,pB2,pB3,pB4,pB5,pB6,pB7, jn)
            PROC_BATCH(sA0,sA1,sA2,sA3,sA4,sA5,sA6,sA7,
                       pA0,pA1,pA2,pA3,pA4,pA5,pA6,pA7, j)
            j = jn;
            if (j >= end) break;
            jn = j + 8;
            if (jn < end)
                LOAD_BATCH(sA0,sA1,sA2,sA3,sA4,sA5,sA6,sA7,
                           pA0,pA1,pA2,pA3,pA4,pA5,pA6,pA7, jn)
            PROC_BATCH(sB0,sB1,sB2,sB3,sB4,sB5,sB6,sB7,
                       pB0,pB1,pB2,pB3,pB4,pB5,pB6,pB7, j)
            j = jn;
            if (j >= end) break;
        }
    }
#undef LOAD_BATCH
#undef PROC_BATCH

    // epilogue: softmax-normalize, +bias, ReLU, proj2 partial for this head
    float inv = 1.f / den;               // den>0 (self-loop guaranteed)
    const float4* b4 = (const float4*)b1;
    float4 ba = b4[h * 8 + sub * 2 + 0];
    float4 bb = b4[h * 8 + sub * 2 + 1];
    float o0 = fmaxf(fmaf(a0[0], inv, ba.x), 0.f);
    float o1 = fmaxf(fmaf(a0[1], inv, ba.y), 0.f);
    float o2 = fmaxf(fmaf(a1[0], inv, ba.z), 0.f);
    float o3 = fmaxf(fmaf(a1[1], inv, ba.w), 0.f);
    float o4 = fmaxf(fmaf(a2[0], inv, bb.x), 0.f);
    float o5 = fmaxf(fmaf(a2[1], inv, bb.y), 0.f);
    float o6 = fmaxf(fmaf(a3[0], inv, bb.z), 0.f);
    float o7 = fmaxf(fmaf(a3[1], inv, bb.w), 0.f);
    // W2 row-major (256,2): rows rb = h*32 + sub*8 .. +7; float4 = 2 rows
    const float4* W4 = (const float4*)W2;
    float4 wA = W4[h * 16 + sub * 4 + 0];
    float4 wB = W4[h * 16 + sub * 4 + 1];
    float4 wC = W4[h * 16 + sub * 4 + 2];
    float4 wD = W4[h * 16 + sub * 4 + 3];
    float d0 = o0 * wA.x + o1 * wA.z + o2 * wB.x + o3 * wB.z
             + o4 * wC.x + o5 * wC.z + o6 * wD.x + o7 * wD.z;
    float d1 = o0 * wA.y + o1 * wA.w + o2 * wB.y + o3 * wB.w
             + o4 * wC.y + o5 * wC.w + o6 * wD.y + o7 * wD.w;
    // reduce across the node's 4 subs (lanes 4n..4n+3)
    d0 += __shfl_xor(d0, 1);  d0 += __shfl_xor(d0, 2);
    d1 += __shfl_xor(d1, 1);  d1 += __shfl_xor(d1, 2);
    if (sub == 0 && alive)
        hpartT[(size_t)h * N_NODES + node] = (float2){d0, d1};   // coalesced per wave
}

// ---------------- sum head partials -> packed layer-2 record ----------------
// pk[n] = {xp2.x, xp2.y, as2, ad2}: one 16B gather per edge in k_agg2.
// hpartT is head-major [8][N]; each plane read coalesced.
__global__ void k_post(const float2* __restrict__ hpartT, const float* __restrict__ as2w,
                       const float* __restrict__ ad2w, float4* __restrict__ pk) {
    int n = blockIdx.x * 256 + threadIdx.x;
    if (n >= N_NODES) return;
    float d0 = 0.f, d1 = 0.f;
    #pragma unroll
    for (int h = 0; h < 8; ++h) {
        float2 v = hpartT[(size_t)h * N_NODES + n];
        d0 += v.x;
        d1 += v.y;
    }
    float4 r;
    r.x = d0;
    r.y = d1;
    r.z = d0 * as2w[0] + d1 * as2w[1];   // as2
    r.w = d0 * ad2w[0] + d1 * ad2w[1];   // ad2
    pk[n] = r;
}

// ---------------- fused segment-softmax + aggregate, layer 2 (2 channels) ----------------
__global__ void k_agg2(const float4* __restrict__ pk, const int* __restrict__ row_ptr,
                       const int* __restrict__ colb, const float* __restrict__ b2,
                       float* __restrict__ out) {
    int t = threadIdx.x;
    int g = t >> 4, lane = t & 15;
    int n = blockIdx.x * 16 + g;
    int start = row_ptr[n], end = row_ptr[n + 1];
    float adn = pk[n].w;
    float a0 = 0.f, a1 = 0.f, den = 0.f;
    for (int j = start + lane; j < end; j += 16) {
        int s = colb[j];
        float4 r = pk[s];
        float e = r.z + adn;
        e = (e > 0.f) ? e : NEG * e;
        float p = __expf(e);
        den += p;
        a0 = fmaf(p, r.x, a0);
        a1 = fmaf(p, r.y, a1);
    }
    #pragma unroll
    for (int m = 1; m < 16; m <<= 1) {
        a0 += __shfl_xor(a0, m);
        a1 += __shfl_xor(a1, m);
        den += __shfl_xor(den, m);
    }
    if (lane == 0) {
        out[2 * n] = a0 / den + b2[0];
        out[2 * n + 1] = a1 / den + b2[1];
    }
}

extern "C" void kernel_launch(void* const* d_in, const int* in_sizes, int n_in,
                              void* d_out, int out_size, void* d_ws, size_t ws_size,
                              hipStream_t stream) {
    const float* x     = (const float*)d_in[0];
    const int*   ei    = (const int*)d_in[1];
    const float* W1    = (const float*)d_in[2];
    const float* asrc1 = (const float*)d_in[3];
    const float* adst1 = (const float*)d_in[4];
    const float* b1    = (const float*)d_in[5];
    const float* W2    = (const float*)d_in[6];
    const float* asrc2 = (const float*)d_in[7];
    const float* adst2 = (const float*)d_in[8];
    const float* b2    = (const float*)d_in[9];
    float* out = (float*)d_out;

    char* ws = (char*)d_ws;
    unsigned short* xph = (unsigned short*)(ws + 0);  // 25,600,000 B (bf16, head-major)
    bf16x8* Wfrag  = (bf16x8*)(ws + 25600000);      //    131,072 B (B frags)
    float2* hpartT = (float2*)(ws + 25800000);      //  3,200,000 B (head-major proj2 partials)
    float* pst     = (float*)(ws + 29000000);       // 27,200,000 B (per-edge p, node-major)
    float* pstT    = (float*)(ws + 56200000);       // 27,200,000 B (per-edge p, head-major)
    float* as1n    = (float*)(ws + 102400000);      //  1,600,000 B ([50000][8])
    float* ad1n    = (float*)(ws + 104000000);      //  1,600,000 B ([50000][8])
    float4* pk     = (float4*)(ws + 105600000);     //    800,000 B (packed layer-2 records)
    int*   counts  = (int*)  (ws + 106400000);      //    200,000 B
    int*   fill    = (int*)  (ws + 106600000);      //    200,000 B (contig w/ counts)
    int*   row_ptr = (int*)  (ws + 106800000);      //    200,064 B
    int*   colb    = (int*)  (ws + 107000064);      //  3,400,000 B
    int*   bsums   = (int*)  (ws + 110400064);      //        256 B

    hipMemsetAsync(counts, 0, 400000, stream);      // counts + fill

    int egrid = (EP + 255) / 256;
    k_hist      <<<egrid,       256, 0, stream>>>(ei, counts);
    k_scan_block<<<SCAN_BLOCKS, 256, 0, stream>>>(counts, row_ptr, bsums);
    k_scan_add  <<<SCAN_BLOCKS, 256, 0, stream>>>(row_ptr, bsums);

    k_cvtWfrag  <<<32,     256, 0, stream>>>(W1, Wfrag);
    k_gemm1m   <<<GM_GRID, 256, 0, stream>>>(x, Wfrag, xph, asrc1, adst1, as1n, ad1n);
    // scatter AFTER gemm: fuses per-edge p computation for all 8 heads
    k_scatter   <<<egrid,   256, 0, stream>>>(ei, row_ptr, fill, colb, as1n, ad1n, pst);
    k_pT        <<<egrid,   256, 0, stream>>>(pst, pstT);
    k_aggh     <<<AGH_GRID, 256, 0, stream>>>((const uint4*)xph, pstT, row_ptr, colb,
                                              b1, W2, hpartT);
    k_post     <<<196,     256, 0, stream>>>(hpartT, asrc2, adst2, pk);
    k_agg2     <<<3125,    256, 0, stream>>>(pk, row_ptr, colb, b2, out);
}